// Round 6
// baseline (320.326 us; speedup 1.0000x reference)
//
#include <hip/hip_runtime.h>
#include <stdint.h>

#define MDIM 8192
#define NDIM 1536
#define KDIM 3072

#define BM 256
#define BN 128
#define BK 64            // one K-tile = two 32-k planes in the proven swizzled layout
#define NGB 512          // 256 full-half jobs (24 kt) + 256 skip jobs (32 kt) = 56 kt/CU exact

#define NMB ((KDIM / 64) * (NDIM / 64))
#define NCVT ((MDIM * KDIM / 4) / 256)

typedef unsigned short u16;
typedef float  f32x4  __attribute__((ext_vector_type(4)));
typedef __bf16 bf16x8 __attribute__((ext_vector_type(8)));

__device__ __forceinline__ u16 f2bf(float f) {
    union { float f; unsigned int u; } v; v.f = f;
    unsigned int u = v.u;
    return (u16)((u + 0x7fffu + ((u >> 16) & 1u)) >> 16);  // RNE
}

// ---------------- fused prep (R0/R2-proven): make_b blocks, then cvt_x blocks ----------------
// Also (re)zeroes the flag zone: Bt rows n<512, k in [1024,1536) have mask==0 -> exact 0x0000,
// and that k-range is excluded from every gemm k-list -> safe scratch for split-K flags.
__global__ void prep_kernel(const float* __restrict__ w, const float* __restrict__ mask,
                            u16* __restrict__ Bt,
                            const float4* __restrict__ x, ushort4* __restrict__ xb) {
    const int t = threadIdx.x;
    if (blockIdx.x < NMB) {
        __shared__ float sw[64][65];
        const int kb = blockIdx.x % (KDIM / 64);
        const int nb = blockIdx.x / (KDIM / 64);
        const int k0 = kb * 64, n0 = nb * 64;
        {
            const int c4 = t & 15;
            const int r  = t >> 4;
#pragma unroll
            for (int rr = 0; rr < 4; ++rr) {
                int row = rr * 16 + r;
                float4 v = *(const float4*)&w[(size_t)(k0 + row) * NDIM + n0 + c4 * 4];
                sw[row][c4 * 4 + 0] = v.x;
                sw[row][c4 * 4 + 1] = v.y;
                sw[row][c4 * 4 + 2] = v.z;
                sw[row][c4 * 4 + 3] = v.w;
            }
        }
        __syncthreads();
        {
            const int n  = t >> 2;
            const int ks = (t & 3) * 16;
#pragma unroll
            for (int j = 0; j < 4; ++j) {
                int k = ks + j * 4;
                float4 mv = *(const float4*)&mask[(size_t)(n0 + n) * KDIM + k0 + k];
                ushort4 o;
                o.x = f2bf(mv.x * sw[k + 0][n]);
                o.y = f2bf(mv.y * sw[k + 1][n]);
                o.z = f2bf(mv.z * sw[k + 2][n]);
                o.w = f2bf(mv.w * sw[k + 3][n]);
                *(ushort4*)&Bt[(size_t)(n0 + n) * KDIM + k0 + k] = o;
            }
        }
    } else {
        int i = (blockIdx.x - NMB) * 256 + t;
        float4 v = x[i];
        ushort4 o;
        o.x = f2bf(v.x); o.y = f2bf(v.y); o.z = f2bf(v.z); o.w = f2bf(v.w);
        xb[i] = o;
    }
}

// ---------------- GEMM: 8-phase counted-vmcnt template (T3+T4+T5), 256x128, 8 waves ----------------
// R5-proven inner schedule (918 TF steady). This round: perfect load balance at 1 block/CU.
//   jobs: 256 full-halves (cls1, 24 kt: k [0,1536) or [1536,3072)) at bik 0..255 (round 1,
//   pairs co-resident -> ~zero flag wait), then 256 skip jobs (32 kt) backfill. 56 kt/CU exact.
// Split-K combine: low half writes acc+bias to C, fence+flag; high half spins, then C += acc.
// Flags: 1 uint per full tile in Bt's dead zone (row i<128, k=1024), prep-zeroed each launch.
// K-skip (exact, 64-aligned): cls0 (n<512): k [0,1024)u[1536,2560); cls2: [512,1536)u[2048,3072).
__device__ __forceinline__ void gload_lds16(const void* g, void* l) {
    __builtin_amdgcn_global_load_lds(
        (const __attribute__((address_space(1))) unsigned int*)g,
        (__attribute__((address_space(3))) unsigned int*)l, 16, 0, 0);
}

#define BARR  __builtin_amdgcn_s_barrier()
#define PRIO1 __builtin_amdgcn_s_setprio(1)
#define PRIO0 __builtin_amdgcn_s_setprio(0)
#define VM(n) asm volatile("s_waitcnt vmcnt(" #n ")" ::: "memory")

__global__ void __launch_bounds__(512, 2)
gemm_kernel(const u16* __restrict__ Ag,  // [M][K] bf16
            const u16* Bg,               // [N][K] bf16 (no restrict: flag zone aliases)
            const float* __restrict__ bias,
            float* __restrict__ C,       // [M][N] fp32
            unsigned* flags) {           // = (unsigned*)Bt; flag i at uint idx i*1536+512
    extern __shared__ u16 smem[];        // 96 KiB: A 64K (4 planes x 256 x 32), B 32K
    u16* sAb = smem;                     // [(buf*2+plane)][256][32]
    u16* sBb = smem + 32768;             // [(buf*2+plane)][128][32]

    const int tid  = threadIdx.x;
    const int wv   = tid >> 6;           // 0..7
    const int lane = tid & 63;

    // job decode; XCD r -> by in [4r,4r+4) banding for all groups
    const int bik = blockIdx.x;
    int bx, by, cls, half = 0, fullidx = 0;
    if (bik < 256) {                     // full-half jobs
        fullidx = bik & 127;
        half    = bik >> 7;
        by = (fullidx & 7) * 4 + ((fullidx >> 3) & 3);
        bx = 4 + (fullidx >> 5);
        cls = 1;
    } else {                             // skip jobs
        const int s = bik - 256;
        by = (s & 7) * 4 + ((s >> 3) & 3);
        const int r = s >> 5;            // 0..7
        bx = r < 4 ? r : r + 4;
        cls = bx >> 2;                   // 0 or 2
    }
    const int m0 = by * BM, n0 = bx * BN;

    int ksplit, kb0, kb1, NT;
    if (cls == 1)      { ksplit = 24; kb0 = half ? 1536 : 0; kb1 = 0; NT = 24; }
    else if (cls == 0) { ksplit = 16; kb0 = 0;   kb1 = 1536; NT = 32; }
    else               { ksplit = 16; kb0 = 512; kb1 = 2048; NT = 32; }
    const int NI = NT >> 1;
    auto kof = [&](int i) { return i < ksplit ? kb0 + i * 64 : kb1 + (i - ksplit) * 64; };

    // staging addressing (proven plane-swizzle: source chunk xor, linear LDS dest)
    const int srow = lane >> 2;
    const int scol = ((lane & 3) ^ ((lane >> 3) & 3)) * 8;
    const u16* gA = Ag + (size_t)(m0 + wv * 16 + srow) * KDIM + scol;
    const u16* gB = Bg + (size_t)(n0 + wv * 16 + srow) * KDIM + scol;
    u16* dA0 = &sAb[(wv * 16) * 32];
    u16* dA1 = &sAb[(wv * 16 + 128) * 32];
    u16* dB  = &sBb[(wv * 16) * 32];

#define SA(b, p, ki) { gload_lds16(gA + (ki) + (p) * 32,                     dA0 + ((b) * 2 + (p)) * 8192); \
                       gload_lds16(gA + (ki) + (p) * 32 + (size_t)128 * KDIM, dA1 + ((b) * 2 + (p)) * 8192); }
#define SB(b, p, ki)   gload_lds16(gB + (ki) + (p) * 32,                     dB  + ((b) * 2 + (p)) * 4096);

    // fragment addressing (proven swizzle)
    const int wm = (wv >> 1) * 64;
    const int wn = (wv & 1) * 64;
    const int fr = lane & 15;
    const int fq = lane >> 4;
    const int fsw = (fq ^ ((fr >> 1) & 3)) * 8;

#define AFRAG(b, kk, mt) (*(const bf16x8*)&sAb[(((b) * 2 + (kk)) * 256 + wm + (mt) * 16 + fr) * 32 + fsw])
#define BFRAG(b, kk, nt) (*(const bf16x8*)&sBb[(((b) * 2 + (kk)) * 128 + wn + (nt) * 16 + fr) * 32 + fsw])
#define MF(mt, nt, xa, xb_) acc[mt][nt] = __builtin_amdgcn_mfma_f32_16x16x32_bf16(xa, xb_, acc[mt][nt], 0, 0, 0)
#define M8(mA, mB, xA, xB, b0_, b1_, b2_, b3_) \
    MF(mA, 0, xA, b0_); MF(mA, 1, xA, b1_); MF(mA, 2, xA, b2_); MF(mA, 3, xA, b3_); \
    MF(mB, 0, xB, b0_); MF(mB, 1, xB, b1_); MF(mB, 2, xB, b2_); MF(mB, 3, xB, b3_);

    f32x4 acc[4][4] = {};

    // prologue: tile0 complete {B0,A0,B1,A1}, tile1 partial {B0,A0,B1}; tile1.A1 comes at P1
    {
        const int k0 = kof(0), k1 = kof(1);
        SB(0, 0, k0); SA(0, 0, k0); SB(0, 1, k0); SA(0, 1, k0);
        SB(1, 0, k1); SA(1, 0, k1); SB(1, 1, k1);
    }
    VM(4);       // tile0's 6 done (only tile1's 4 newer)
    BARR;

    // one quad = 4 phases over one buffer; S1..S4 = per-phase stage units, VW = counted wait
#define QUAD(bb, S1, S2, S3, S4, VW)                                              \
    {                                                                             \
        { S1; }                                                                   \
        {                                                                         \
            bf16x8 b0 = BFRAG(bb, 0, 0), b1 = BFRAG(bb, 0, 1),                    \
                   b2 = BFRAG(bb, 0, 2), b3 = BFRAG(bb, 0, 3);                    \
            bf16x8 a0 = AFRAG(bb, 0, 0), a1 = AFRAG(bb, 0, 1);                    \
            BARR; PRIO1; M8(0, 1, a0, a1, b0, b1, b2, b3); PRIO0; BARR;           \
            { S2; }                                                               \
            bf16x8 a2 = AFRAG(bb, 0, 2), a3 = AFRAG(bb, 0, 3);                    \
            BARR; PRIO1; M8(2, 3, a2, a3, b0, b1, b2, b3); PRIO0; BARR;           \
        }                                                                         \
        { S3; }                                                                   \
        {                                                                         \
            bf16x8 b0 = BFRAG(bb, 1, 0), b1 = BFRAG(bb, 1, 1),                    \
                   b2 = BFRAG(bb, 1, 2), b3 = BFRAG(bb, 1, 3);                    \
            bf16x8 a0 = AFRAG(bb, 1, 0), a1 = AFRAG(bb, 1, 1);                    \
            BARR; PRIO1; M8(0, 1, a0, a1, b0, b1, b2, b3); PRIO0; BARR;           \
            { S4; }                                                               \
            bf16x8 a2 = AFRAG(bb, 1, 2), a3 = AFRAG(bb, 1, 3);                    \
            BARR; PRIO1; M8(2, 3, a2, a3, b0, b1, b2, b3); PRIO0;                 \
            { VW; }                                                               \
            BARR;                                                                 \
        }                                                                         \
    }

    for (int i = 0; i < NI; ++i) {
        const bool nl  = (i + 1 < NI);
        const int  kn1 = kof(2 * i + 1);
        const int  kn2 = nl ? kof(2 * i + 2) : 0;
        const int  kn3 = nl ? kof(2 * i + 3) : 0;

        // phases 1-4: tile t (buf0); stage t+1.A1, then t+2.{B0,A0,B1} -> buf0
        QUAD(0,
             SA(1, 1, kn1),
             if (nl) { SB(0, 0, kn2); },
             if (nl) { SA(0, 0, kn2); },
             if (nl) { SB(0, 1, kn2); },
             if (nl) { VM(4); } else { VM(0); });

        // phases 5-8: tile t+1 (buf1); stage t+2.A1 -> buf0, then t+3.{B0,A0,B1} -> buf1
        QUAD(1,
             if (nl) { SA(0, 1, kn2); },
             if (nl) { SB(1, 0, kn3); },
             if (nl) { SA(1, 0, kn3); },
             if (nl) { SB(1, 1, kn3); },
             if (nl) { VM(4); });
    }

    // epilogue: C/D layout col = lane&15, row = (lane>>4)*4 + reg  [m89-verified]
    if (cls != 1) {
        // skip jobs: sole owner of the C tile
#pragma unroll
        for (int nt = 0; nt < 4; ++nt) {
            int n = n0 + wn + nt * 16 + fr;
            float bv = bias[n];
#pragma unroll
            for (int mt = 0; mt < 4; ++mt) {
                int m = m0 + wm + mt * 16 + fq * 4;
#pragma unroll
                for (int r = 0; r < 4; ++r)
                    C[(size_t)(m + r) * NDIM + n] = acc[mt][nt][r] + bv;
            }
        }
    } else {
        unsigned* flag = flags + (size_t)fullidx * 1536 + 512;  // Bt dead zone, prep-zeroed
        if (half == 0) {
            // low half: partial + bias, then publish
#pragma unroll
            for (int nt = 0; nt < 4; ++nt) {
                int n = n0 + wn + nt * 16 + fr;
                float bv = bias[n];
#pragma unroll
                for (int mt = 0; mt < 4; ++mt) {
                    int m = m0 + wm + mt * 16 + fq * 4;
#pragma unroll
                    for (int r = 0; r < 4; ++r)
                        C[(size_t)(m + r) * NDIM + n] = acc[mt][nt][r] + bv;
                }
            }
            __threadfence();          // each thread's C stores device-visible
            __syncthreads();          // all threads fenced
            if (tid == 0) atomicExch(flag, 1u);
        } else {
            if (tid == 0) { while (atomicAdd(flag, 0u) == 0u) __builtin_amdgcn_s_sleep(8); }
            __syncthreads();
            __threadfence();
            // high half: combine (sole owner after flag)
#pragma unroll
            for (int nt = 0; nt < 4; ++nt) {
                int n = n0 + wn + nt * 16 + fr;
#pragma unroll
                for (int mt = 0; mt < 4; ++mt) {
                    int m = m0 + wm + mt * 16 + fq * 4;
#pragma unroll
                    for (int r = 0; r < 4; ++r) {
                        size_t idx = (size_t)(m + r) * NDIM + n;
                        C[idx] = C[idx] + acc[mt][nt][r];
                    }
                }
            }
        }
    }
}

extern "C" void kernel_launch(void* const* d_in, const int* in_sizes, int n_in,
                              void* d_out, int out_size, void* d_ws, size_t ws_size,
                              hipStream_t stream) {
    const float* x    = (const float*)d_in[0];   // [8192][3072]
    const float* w    = (const float*)d_in[1];   // [3072][1536]
    const float* bias = (const float*)d_in[2];   // [1536]
    const float* mask = (const float*)d_in[3];   // [1536][3072]
    float* out = (float*)d_out;                  // [8192][1536]

    u16* xb = (u16*)d_ws;                                   // 50331648 B
    u16* Bt = (u16*)((char*)d_ws + (size_t)50331648);       //  9437184 B

    static bool attr_done = false;
    if (!attr_done) {
        (void)hipFuncSetAttribute((const void*)gemm_kernel,
                                  hipFuncAttributeMaxDynamicSharedMemorySize, 98304);
        attr_done = true;
    }

    prep_kernel<<<NMB + NCVT, 256, 0, stream>>>(w, mask, Bt, (const float4*)x, (ushort4*)xb);
    gemm_kernel<<<NGB, 512, 98304, stream>>>(xb, Bt, bias, out, (unsigned*)Bt);
}

// Round 7
// 258.611 us; speedup vs baseline: 1.2386x; 1.2386x over previous
//
#include <hip/hip_runtime.h>
#include <stdint.h>

#define MDIM 8192
#define NDIM 1536
#define KDIM 3072

#define BM 128
#define BN 128
#define BK 64            // one K-tile = two 32-k planes in the proven swizzled layout
#define NGB ((MDIM / BM) * (NDIM / BN))   // 768 blocks = 2/CU + 256 backfill

#define NMB ((KDIM / 64) * (NDIM / 64))
#define NCVT ((MDIM * KDIM / 4) / 256)

typedef unsigned short u16;
typedef float  f32x4  __attribute__((ext_vector_type(4)));
typedef __bf16 bf16x8 __attribute__((ext_vector_type(8)));

__device__ __forceinline__ u16 f2bf(float f) {
    union { float f; unsigned int u; } v; v.f = f;
    unsigned int u = v.u;
    return (u16)((u + 0x7fffu + ((u >> 16) & 1u)) >> 16);  // RNE
}

// ---------------- fused prep (R0/R2-proven): make_b blocks, then cvt_x blocks ----------------
__global__ void prep_kernel(const float* __restrict__ w, const float* __restrict__ mask,
                            u16* __restrict__ Bt,
                            const float4* __restrict__ x, ushort4* __restrict__ xb) {
    const int t = threadIdx.x;
    if (blockIdx.x < NMB) {
        __shared__ float sw[64][65];
        const int kb = blockIdx.x % (KDIM / 64);
        const int nb = blockIdx.x / (KDIM / 64);
        const int k0 = kb * 64, n0 = nb * 64;
        {
            const int c4 = t & 15;
            const int r  = t >> 4;
#pragma unroll
            for (int rr = 0; rr < 4; ++rr) {
                int row = rr * 16 + r;
                float4 v = *(const float4*)&w[(size_t)(k0 + row) * NDIM + n0 + c4 * 4];
                sw[row][c4 * 4 + 0] = v.x;
                sw[row][c4 * 4 + 1] = v.y;
                sw[row][c4 * 4 + 2] = v.z;
                sw[row][c4 * 4 + 3] = v.w;
            }
        }
        __syncthreads();
        {
            const int n  = t >> 2;
            const int ks = (t & 3) * 16;
#pragma unroll
            for (int j = 0; j < 4; ++j) {
                int k = ks + j * 4;
                float4 mv = *(const float4*)&mask[(size_t)(n0 + n) * KDIM + k0 + k];
                ushort4 o;
                o.x = f2bf(mv.x * sw[k + 0][n]);
                o.y = f2bf(mv.y * sw[k + 1][n]);
                o.z = f2bf(mv.z * sw[k + 2][n]);
                o.w = f2bf(mv.w * sw[k + 3][n]);
                *(ushort4*)&Bt[(size_t)(n0 + n) * KDIM + k0 + k] = o;
            }
        }
    } else {
        int i = (blockIdx.x - NMB) * 256 + t;
        float4 v = x[i];
        ushort4 o;
        o.x = f2bf(v.x); o.y = f2bf(v.y); o.z = f2bf(v.z); o.w = f2bf(v.w);
        xb[i] = o;
    }
}

// ---------------- GEMM: 8-phase counted-vmcnt, 128x128, 8 waves, 2 blocks/CU ----------------
// R5-proven schedule at half tile: 4 stage-units/tile {B0,A0,B1,A1} of 1 gload each,
// counted VM(3); plane-overwrite discipline identical (a plane is staged only after all
// its frag reads were issued a barrier earlier). 64 KiB LDS -> 2 blocks/CU, so per-CU
// queues pack perfectly: {48,32,32} = 112 kt = 2x56 ideal (vs R5's 64-unit makespan).
// Jobs: 256 full-K (bik 0..255, one per CU breadth-first) + 512 skip. K-skip exact,
// 64-aligned: cls0 (n<512): k [0,1024)u[1536,2560); cls2 (n>=1024): [512,1536)u[2048,3072).
// XCD banding: by = (bik&7)*8 + ... keeps each XCD on an 8-wide by-band.
__device__ __forceinline__ void gload_lds16(const void* g, void* l) {
    __builtin_amdgcn_global_load_lds(
        (const __attribute__((address_space(1))) unsigned int*)g,
        (__attribute__((address_space(3))) unsigned int*)l, 16, 0, 0);
}

#define BARR  __builtin_amdgcn_s_barrier()
#define PRIO1 __builtin_amdgcn_s_setprio(1)
#define PRIO0 __builtin_amdgcn_s_setprio(0)
#define VM(n) asm volatile("s_waitcnt vmcnt(" #n ")" ::: "memory")

#define PLANE 4096   // u16 per k-plane (128 rows * 32)

__global__ void __launch_bounds__(512, 4)
gemm_kernel(const u16* __restrict__ Ag,  // [M][K] bf16
            const u16* __restrict__ Bg,  // [N][K] bf16
            const float* __restrict__ bias,
            float* __restrict__ C) {     // [M][N] fp32
    extern __shared__ u16 smem[];        // 64 KiB: A 32K (4 planes x 128 x 32), B 32K
    u16* sAb = smem;                     // [(buf*2+plane)][128][32]
    u16* sBb = smem + 16384;             // [(buf*2+plane)][128][32]

    const int tid  = threadIdx.x;
    const int wv   = tid >> 6;           // 0..7
    const int lane = tid & 63;

    // bik 0..255 = full-K (bx 4..7), 256..767 = skip; XCD r -> by in [8r, 8r+8)
    const int bik = blockIdx.x;
    int bx, by, cls;
    if (bik < 256) {
        by = (bik & 7) * 8 + ((bik >> 3) & 7);
        bx = 4 + (bik >> 6);
        cls = 1;
    } else {
        const int s = bik - 256;         // 0..511
        by = (s & 7) * 8 + ((s >> 3) & 7);
        const int b = s >> 6;            // 0..7
        bx = b < 4 ? b : b + 4;
        cls = bx >> 2;                   // 0 or 2
    }
    const int m0 = by * BM, n0 = bx * BN;

    int ksplit, kb0, kb1, NT;
    if (cls == 1)      { ksplit = 48; kb0 = 0;   kb1 = 0;    NT = 48; }
    else if (cls == 0) { ksplit = 16; kb0 = 0;   kb1 = 1536; NT = 32; }
    else               { ksplit = 16; kb0 = 512; kb1 = 2048; NT = 32; }
    const int NI = NT >> 1;
    auto kof = [&](int i) { return i < ksplit ? kb0 + i * 64 : kb1 + (i - ksplit) * 64; };

    // staging addressing (proven plane-swizzle: source chunk xor, linear LDS dest)
    const int srow = lane >> 2;
    const int scol = ((lane & 3) ^ ((lane >> 3) & 3)) * 8;
    const u16* gA = Ag + (size_t)(m0 + wv * 16 + srow) * KDIM + scol;
    const u16* gB = Bg + (size_t)(n0 + wv * 16 + srow) * KDIM + scol;
    u16* dA = &sAb[(wv * 16) * 32];
    u16* dB = &sBb[(wv * 16) * 32];

#define SA(b, p, ki) gload_lds16(gA + (ki) + (p) * 32, dA + ((b) * 2 + (p)) * PLANE);
#define SB(b, p, ki) gload_lds16(gB + (ki) + (p) * 32, dB + ((b) * 2 + (p)) * PLANE);

    // fragment addressing (proven swizzle); waves 4M x 2N, wave tile 32x64
    const int wm = (wv >> 1) * 32;
    const int wn = (wv & 1) * 64;
    const int fr = lane & 15;
    const int fq = lane >> 4;
    const int fsw = (fq ^ ((fr >> 1) & 3)) * 8;

#define AFRAG(b, kk, mt) (*(const bf16x8*)&sAb[(((b) * 2 + (kk)) * 128 + wm + (mt) * 16 + fr) * 32 + fsw])
#define BFRAG(b, kk, nt) (*(const bf16x8*)&sBb[(((b) * 2 + (kk)) * 128 + wn + (nt) * 16 + fr) * 32 + fsw])
#define MF(mt, nt, xa, xb_) acc[mt][nt] = __builtin_amdgcn_mfma_f32_16x16x32_bf16(xa, xb_, acc[mt][nt], 0, 0, 0)
#define M4(xa0, xa1, xb0, xb1, ntA, ntB) \
    MF(0, ntA, xa0, xb0); MF(0, ntB, xa0, xb1); \
    MF(1, ntA, xa1, xb0); MF(1, ntB, xa1, xb1);

    f32x4 acc[2][4] = {};

    // prologue: tile0 complete {B0,A0,B1,A1}, tile1 partial {B0,A0,B1}; tile1.A1 at S1
    {
        const int k0 = kof(0), k1 = kof(1);
        SB(0, 0, k0); SA(0, 0, k0); SB(0, 1, k0); SA(0, 1, k0);
        SB(1, 0, k1); SA(1, 0, k1); SB(1, 1, k1);
    }
    VM(3);       // tile0's 4 done (only tile1's 3 newer)
    BARR;

    // one quad = 4 phases over one buffer. Read schedule guards plane overwrites:
    //  Ia reads ALL kk=0 frags (b0..b3,a0,a1) -> S2 (B plane0) & S3 (A plane0) safe after;
    //  IIa reads ALL kk=1 frags -> S4 (B plane1) safe; A plane1 staged next quad's S1.
#define QUAD(bb, S1, S2, S3, S4, VW)                                              \
    {                                                                             \
        { S1; }                                                                   \
        bf16x8 a0 = AFRAG(bb, 0, 0), a1 = AFRAG(bb, 0, 1);                        \
        bf16x8 b0 = BFRAG(bb, 0, 0), b1 = BFRAG(bb, 0, 1),                        \
               b2 = BFRAG(bb, 0, 2), b3 = BFRAG(bb, 0, 3);                        \
        BARR; PRIO1; M4(a0, a1, b0, b1, 0, 1); PRIO0; BARR;                       \
        { S2; }                                                                   \
        BARR; PRIO1; M4(a0, a1, b2, b3, 2, 3); PRIO0; BARR;                       \
        { S3; }                                                                   \
        bf16x8 c0 = AFRAG(bb, 1, 0), c1 = AFRAG(bb, 1, 1);                        \
        bf16x8 d0 = BFRAG(bb, 1, 0), d1 = BFRAG(bb, 1, 1),                        \
               d2 = BFRAG(bb, 1, 2), d3 = BFRAG(bb, 1, 3);                        \
        BARR; PRIO1; M4(c0, c1, d0, d1, 0, 1); PRIO0; BARR;                       \
        { S4; }                                                                   \
        BARR; PRIO1; M4(c0, c1, d2, d3, 2, 3); PRIO0;                             \
        { VW; }                                                                   \
        BARR;                                                                     \
    }

    for (int i = 0; i < NI; ++i) {
        const bool nl  = (i + 1 < NI);
        const int  kn1 = kof(2 * i + 1);
        const int  kn2 = nl ? kof(2 * i + 2) : 0;
        const int  kn3 = nl ? kof(2 * i + 3) : 0;

        // phases 1-4: tile t (buf0); stage t+1.A1, then t+2.{B0,A0,B1} -> buf0
        QUAD(0,
             SA(1, 1, kn1),
             if (nl) { SB(0, 0, kn2); },
             if (nl) { SA(0, 0, kn2); },
             if (nl) { SB(0, 1, kn2); },
             if (nl) { VM(3); } else { VM(0); });

        // phases 5-8: tile t+1 (buf1); stage t+2.A1 -> buf0, then t+3.{B0,A0,B1} -> buf1
        QUAD(1,
             if (nl) { SA(0, 1, kn2); },
             if (nl) { SB(1, 0, kn3); },
             if (nl) { SA(1, 0, kn3); },
             if (nl) { SB(1, 1, kn3); },
             if (nl) { VM(3); });
    }

    // epilogue: C/D layout col = lane&15, row = (lane>>4)*4 + reg  [m89-verified]
#pragma unroll
    for (int nt = 0; nt < 4; ++nt) {
        int n = n0 + wn + nt * 16 + fr;
        float bv = bias[n];
#pragma unroll
        for (int mt = 0; mt < 2; ++mt) {
            int m = m0 + wm + mt * 16 + fq * 4;
#pragma unroll
            for (int r = 0; r < 4; ++r)
                C[(size_t)(m + r) * NDIM + n] = acc[mt][nt][r] + bv;
        }
    }
}

extern "C" void kernel_launch(void* const* d_in, const int* in_sizes, int n_in,
                              void* d_out, int out_size, void* d_ws, size_t ws_size,
                              hipStream_t stream) {
    const float* x    = (const float*)d_in[0];   // [8192][3072]
    const float* w    = (const float*)d_in[1];   // [3072][1536]
    const float* bias = (const float*)d_in[2];   // [1536]
    const float* mask = (const float*)d_in[3];   // [1536][3072]
    float* out = (float*)d_out;                  // [8192][1536]

    u16* xb = (u16*)d_ws;                                   // 50331648 B
    u16* Bt = (u16*)((char*)d_ws + (size_t)50331648);       //  9437184 B

    static bool attr_done = false;
    if (!attr_done) {
        (void)hipFuncSetAttribute((const void*)gemm_kernel,
                                  hipFuncAttributeMaxDynamicSharedMemorySize, 65536);
        attr_done = true;
    }

    prep_kernel<<<NMB + NCVT, 256, 0, stream>>>(w, mask, Bt, (const float4*)x, (ushort4*)xb);
    gemm_kernel<<<NGB, 512, 65536, stream>>>(xb, Bt, bias, out);
}